// Round 2
// baseline (17765.524 us; speedup 1.0000x reference)
//
#include <hip/hip_runtime.h>
#include <hip/hip_bf16.h>
#include <math.h>

#define B_    2
#define S_    2048
#define DIN   2048
#define DOUT  2048
#define H_    16
#define RD_   64
#define L_    512
#define HD_   128
#define BS_   (B_*S_)   // 4096

// ---------------------------------------------------------------------------
// Generic NT GEMM: C[m][n] = sum_k A[m][k] * B[n][k]
// Requires M,N % 64 == 0, K % 16 == 0. 64x64 tile, 256 threads, 4x4 micro-tile.
// ---------------------------------------------------------------------------
__global__ __launch_bounds__(256) void gemm_nt(
    const float* __restrict__ A, const float* __restrict__ Bm, float* __restrict__ C,
    int M, int N, int K, int lda, int ldb, int ldc)
{
    __shared__ float As[16][68];   // [k][m], pad 68
    __shared__ float Bs[16][68];   // [k][n]

    const int tid = threadIdx.x;
    const int tx = tid & 15, ty = tid >> 4;
    const int m0 = blockIdx.y << 6, n0 = blockIdx.x << 6;

    float acc[4][4];
    #pragma unroll
    for (int i = 0; i < 4; i++)
        #pragma unroll
        for (int j = 0; j < 4; j++) acc[i][j] = 0.f;

    const int kk_l = tid & 15;
    const int mm_l = tid >> 4;

    for (int k0 = 0; k0 < K; k0 += 16) {
        #pragma unroll
        for (int i = 0; i < 4; i++) {
            As[kk_l][mm_l + 16*i] = A [(long long)(m0 + mm_l + 16*i) * lda + k0 + kk_l];
            Bs[kk_l][mm_l + 16*i] = Bm[(long long)(n0 + mm_l + 16*i) * ldb + k0 + kk_l];
        }
        __syncthreads();
        #pragma unroll
        for (int kk = 0; kk < 16; kk++) {
            float4 a4 = *(const float4*)&As[kk][ty << 2];
            float4 b4 = *(const float4*)&Bs[kk][tx << 2];
            float a[4] = {a4.x, a4.y, a4.z, a4.w};
            float b[4] = {b4.x, b4.y, b4.z, b4.w};
            #pragma unroll
            for (int i = 0; i < 4; i++)
                #pragma unroll
                for (int j = 0; j < 4; j++)
                    acc[i][j] += a[i] * b[j];
        }
        __syncthreads();
    }

    #pragma unroll
    for (int i = 0; i < 4; i++) {
        float4 v = {acc[i][0], acc[i][1], acc[i][2], acc[i][3]};
        *(float4*)&C[(long long)(m0 + (ty << 2) + i) * ldc + n0 + (tx << 2)] = v;
    }
}

// ---------------------------------------------------------------------------
// RMSNorm in place over rows of length 512, times weight.
// ---------------------------------------------------------------------------
__global__ __launch_bounds__(256) void rmsnorm_kernel(float* __restrict__ ckv,
                                                      const float* __restrict__ w)
{
    const int row = blockIdx.x;
    const int tid = threadIdx.x;
    float* p = ckv + (long long)row * L_;
    float v0 = p[tid], v1 = p[tid + 256];
    float ss = v0 * v0 + v1 * v1;
    #pragma unroll
    for (int o = 32; o >= 1; o >>= 1) ss += __shfl_xor(ss, o);
    __shared__ float wsum[4];
    if ((tid & 63) == 0) wsum[tid >> 6] = ss;
    __syncthreads();
    float tot = wsum[0] + wsum[1] + wsum[2] + wsum[3];
    float scale = rsqrtf(tot * (1.0f / (float)L_) + 1e-6f);
    p[tid]       = v0 * scale * w[tid];
    p[tid + 256] = v1 * scale * w[tid + 256];
}

// ---------------------------------------------------------------------------
// w_uk_t[h][l][d] = W_UK[h*HD + d][l]
// ---------------------------------------------------------------------------
__global__ __launch_bounds__(256) void transpose_wuk(const float* __restrict__ W_UK,
                                                     float* __restrict__ w_uk_t)
{
    long long idx = (long long)blockIdx.x * 256 + threadIdx.x;  // over H*L*HD
    int d = (int)(idx % HD_);
    long long t = idx / HD_;
    int l = (int)(t % L_);
    int h = (int)(t / L_);
    w_uk_t[idx] = W_UK[(long long)(h * HD_ + d) * L_ + l];
}

// ---------------------------------------------------------------------------
// RoPE (GPT-NeoX style), IN PLACE on q_raw rope cols and kr_raw.
// ---------------------------------------------------------------------------
__global__ __launch_bounds__(256) void rope_kernel(float* __restrict__ q_raw,
                                                   float* __restrict__ kr_raw,
                                                   const int* __restrict__ offp)
{
    const int offset = offp[0];
    long long idx = (long long)blockIdx.x * 256 + threadIdx.x;  // over (B*S)*H*32
    int r = (int)(idx & 31);
    long long t = idx >> 5;
    int h = (int)(t % H_);
    long long m = t / H_;                 // m = b*S + s
    int s = (int)(m % S_);

    float inv = (float)exp(-9.210340371976184 * ((double)r / 32.0)); // 10000^(-r/32)
    float ang = (float)(offset + s) * inv;
    float sn, cs;
    sincosf(ang, &sn, &cs);

    float* q = q_raw + m * 3072 + DOUT + h * RD_;
    float x1 = q[r], x2 = q[r + 32];
    q[r]      = x1 * cs - x2 * sn;
    q[r + 32] = x2 * cs + x1 * sn;

    float* kk = kr_raw + m * (H_ * RD_) + h * RD_;
    x1 = kk[r]; x2 = kk[r + 32];
    kk[r]      = x1 * cs - x2 * sn;
    kk[r + 32] = x2 * cs + x1 * sn;
}

// ---------------------------------------------------------------------------
// Fused flash latent attention:
//   prologue: q_abs_tile = q_content_tile @ w_uk_t[h]   (regs)
//   main:     online-softmax over c_kv (LDS) + k_rope (LDS)
//   epilogue: ctx_tile = acc_tile @ W_UV[h]^T  -> ctx [BS][2048]
// Grid: (S/32, B*H). Block: 256 = 32 Q-rows x 8 chunks.
// Thread (rl,j) owns q_abs/acc cols { j*4+i + k*32 : i<4, k<16 }.
// ---------------------------------------------------------------------------
__global__ __launch_bounds__(256, 2) void flash_kernel(
    const float* __restrict__ q_raw,   // [BS][3072] (rope cols already rotated)
    const float* __restrict__ c_kv,    // [BS][512]
    const float* __restrict__ kr_raw,  // [BS][1024] (rotated, head-major cols)
    const float* __restrict__ w_uk_t,  // [H][512][128]
    const float* __restrict__ W_UV,    // [2048][512]
    const int* __restrict__ offp,
    float* __restrict__ ctx)           // [BS][2048]
{
    __shared__ float smem[32 * 516];   // 66,048 B; unioned:
    float* ckv_s = smem;               //   main: [16][512]
    float* kr_s  = smem + 8192;        //   main: [16][64]
                                       //   prologue: qc [32][132]
                                       //   epilogue: acc [32][516]

    const int offset = offp[0];
    const int bh = blockIdx.y;
    const int b = bh >> 4, h = bh & 15;
    const int r0 = blockIdx.x * 32;
    const int tid = threadIdx.x;
    const int rl = tid >> 3;          // local Q-row 0..31
    const int j  = tid & 7;           // chunk 0..7
    const int srow = r0 + rl;
    const long long mrow = (long long)b * S_ + srow;

    // ---- prologue: qc tile -> LDS ----
    {
        const float* src = q_raw + mrow * 3072 + h * HD_ + j * 16;
        float* dst = &smem[rl * 132 + j * 16];
        #pragma unroll
        for (int i = 0; i < 4; i++)
            ((float4*)dst)[i] = ((const float4*)src)[i];
    }
    __syncthreads();

    float qa[16][4];
    #pragma unroll
    for (int k = 0; k < 16; k++)
        #pragma unroll
        for (int i = 0; i < 4; i++) qa[k][i] = 0.f;

    for (int dc = 0; dc < 128; dc += 16) {
        float4 qc[4];
        #pragma unroll
        for (int i = 0; i < 4; i++) qc[i] = *(const float4*)&smem[rl * 132 + dc + i * 4];
        #pragma unroll
        for (int k = 0; k < 16; k++) {
            #pragma unroll
            for (int i = 0; i < 4; i++) {
                const float4* wp = (const float4*)
                    (w_uk_t + ((long long)(h * L_ + k * 32 + (j << 2) + i)) * HD_ + dc);
                float s = 0.f;
                #pragma unroll
                for (int d4 = 0; d4 < 4; d4++) {
                    float4 w4 = wp[d4];
                    s += qc[d4].x * w4.x + qc[d4].y * w4.y
                       + qc[d4].z * w4.z + qc[d4].w * w4.w;
                }
                qa[k][i] += s;
            }
        }
    }

    // q_rope fragment (global, no LDS dependency)
    float qr[2][4];
    #pragma unroll
    for (int k = 0; k < 2; k++) {
        float4 v = *(const float4*)(q_raw + mrow * 3072 + DOUT + h * RD_ + (j << 2) + k * 32);
        qr[k][0] = v.x; qr[k][1] = v.y; qr[k][2] = v.z; qr[k][3] = v.w;
    }

    float acc[16][4];
    #pragma unroll
    for (int k = 0; k < 16; k++)
        #pragma unroll
        for (int i = 0; i < 4; i++) acc[k][i] = 0.f;

    float m = -INFINITY, l = 0.f;
    const float scale = rsqrtf((float)(HD_ + RD_));

    int tmax = r0 + 32 + offset;
    if (tmax > S_) tmax = S_;

    for (int t0 = 0; t0 < tmax; t0 += 16) {
        __syncthreads();   // previous-iter reads (or prologue reads) done
        const int avail = S_ - t0;
        {
            const float4* csrc4 = (const float4*)(c_kv + ((long long)b * S_ + t0) * L_);
            float4* cdst4 = (float4*)ckv_s;
            #pragma unroll
            for (int i = 0; i < 8; i++) {
                int f4 = i * 256 + tid;
                cdst4[f4] = ((f4 >> 7) < avail) ? csrc4[f4] : make_float4(0.f,0.f,0.f,0.f);
            }
            int krow = tid >> 4, kcol = (tid & 15) << 2;
            const float4 kv = (krow < avail)
                ? *(const float4*)(kr_raw + ((long long)b * S_ + t0 + krow) * (H_*RD_) + h * RD_ + kcol)
                : make_float4(0.f,0.f,0.f,0.f);
            *(float4*)&kr_s[krow * RD_ + kcol] = kv;
        }
        __syncthreads();

        float sc[16];
        #pragma unroll
        for (int ti = 0; ti < 16; ti++) {
            const float* cvrow = &ckv_s[ti * L_];
            float s = 0.f;
            #pragma unroll
            for (int k = 0; k < 16; k++) {
                float4 v = *(const float4*)(cvrow + (j << 2) + (k << 5));
                s += qa[k][0] * v.x + qa[k][1] * v.y + qa[k][2] * v.z + qa[k][3] * v.w;
            }
            const float* krow = &kr_s[ti * RD_];
            #pragma unroll
            for (int k = 0; k < 2; k++) {
                float4 v = *(const float4*)(krow + (j << 2) + (k << 5));
                s += qr[k][0] * v.x + qr[k][1] * v.y + qr[k][2] * v.z + qr[k][3] * v.w;
            }
            s += __shfl_xor(s, 1);
            s += __shfl_xor(s, 2);
            s += __shfl_xor(s, 4);
            sc[ti] = ((t0 + ti) <= (srow + offset)) ? s * scale : -INFINITY;
        }

        float mt = sc[0];
        #pragma unroll
        for (int ti = 1; ti < 16; ti++) mt = fmaxf(mt, sc[ti]);
        float mnew = fmaxf(m, mt);
        float alpha = __expf(m - mnew);
        float pv[16];
        float psum = 0.f;
        #pragma unroll
        for (int ti = 0; ti < 16; ti++) { pv[ti] = __expf(sc[ti] - mnew); psum += pv[ti]; }
        l = l * alpha + psum;
        m = mnew;

        #pragma unroll
        for (int k = 0; k < 16; k++)
            #pragma unroll
            for (int i = 0; i < 4; i++) acc[k][i] *= alpha;

        #pragma unroll
        for (int ti = 0; ti < 16; ti++) {
            const float pt = pv[ti];
            const float* cvrow = &ckv_s[ti * L_];
            #pragma unroll
            for (int k = 0; k < 16; k++) {
                float4 v = *(const float4*)(cvrow + (j << 2) + (k << 5));
                acc[k][0] += pt * v.x; acc[k][1] += pt * v.y;
                acc[k][2] += pt * v.z; acc[k][3] += pt * v.w;
            }
        }
    }

    // ---- epilogue: acc -> LDS [32][516], then ctx tile = acc @ W_UV[h]^T ----
    __syncthreads();
    const float inv_l = 1.0f / l;
    #pragma unroll
    for (int k = 0; k < 16; k++) {
        float4 v = {acc[k][0] * inv_l, acc[k][1] * inv_l,
                    acc[k][2] * inv_l, acc[k][3] * inv_l};
        *(float4*)&smem[rl * 516 + k * 32 + (j << 2)] = v;
    }
    __syncthreads();

    float o[16];
    #pragma unroll
    for (int c = 0; c < 16; c++) o[c] = 0.f;
    const float* wv = W_UV + ((long long)(h * HD_ + j * 16)) * L_;
    for (int lc = 0; lc < 512; lc += 4) {
        float4 a4 = *(const float4*)&smem[rl * 516 + lc];
        #pragma unroll
        for (int c = 0; c < 16; c++) {
            float4 w4 = *(const float4*)&wv[(long long)c * L_ + lc];
            o[c] += a4.x * w4.x + a4.y * w4.y + a4.z * w4.z + a4.w * w4.w;
        }
    }
    float* cp = ctx + ((long long)b * S_ + r0 + rl) * DOUT + h * HD_ + j * 16;
    #pragma unroll
    for (int c4 = 0; c4 < 4; c4++) {
        float4 v = {o[c4*4], o[c4*4+1], o[c4*4+2], o[c4*4+3]};
        ((float4*)cp)[c4] = v;
    }
}

// ---------------------------------------------------------------------------
extern "C" void kernel_launch(void* const* d_in, const int* in_sizes, int n_in,
                              void* d_out, int out_size, void* d_ws, size_t ws_size,
                              hipStream_t stream)
{
    const float* x       = (const float*)d_in[0];
    const float* W_DKV   = (const float*)d_in[1];
    const float* W_KRope = (const float*)d_in[2];
    const float* W_Q     = (const float*)d_in[3];
    const float* W_UK    = (const float*)d_in[4];
    const float* W_UV    = (const float*)d_in[5];
    const float* W_O     = (const float*)d_in[6];
    const float* kvnw    = (const float*)d_in[7];
    const int*   offp    = (const int*)d_in[8];
    float* out = (float*)d_out;

    float* ws = (float*)d_ws;
    float* c_kv   = ws;                      // 2,097,152   [B*S][512]
    float* kr_raw = c_kv   + 2097152;        // 4,194,304   [B*S][1024]
    float* q_raw  = kr_raw + 4194304;        // 12,582,912  [B*S][3072]
    float* w_uk_t = q_raw  + 12582912;       // 1,048,576   [H][512][128]
    float* ctx    = w_uk_t + 1048576;        // 8,388,608   [B*S][2048]
    // total: 28,311,552 floats = 108 MiB

    dim3 blk(256);

    // 1. c_kv_raw = x @ W_DKV^T    [4096 x 512], K=2048
    gemm_nt<<<dim3(512/64, 4096/64), blk, 0, stream>>>(
        x, W_DKV, c_kv, 4096, 512, 2048, 2048, 2048, 512);
    // 2. RMSNorm in place
    rmsnorm_kernel<<<4096, 256, 0, stream>>>(c_kv, kvnw);
    // 3. kr_raw = x @ W_KRope^T    [4096 x 1024]
    gemm_nt<<<dim3(1024/64, 4096/64), blk, 0, stream>>>(
        x, W_KRope, kr_raw, 4096, 1024, 2048, 2048, 2048, 1024);
    // 4. q_raw = x @ W_Q^T         [4096 x 3072]
    gemm_nt<<<dim3(3072/64, 4096/64), blk, 0, stream>>>(
        x, W_Q, q_raw, 4096, 3072, 2048, 2048, 2048, 3072);
    // 5. w_uk transpose
    transpose_wuk<<<4096, 256, 0, stream>>>(W_UK, w_uk_t);
    // 6. RoPE in place (q_raw rope cols, kr_raw)
    rope_kernel<<<8192, 256, 0, stream>>>(q_raw, kr_raw, offp);
    // 7. fused flash latent attention -> ctx
    flash_kernel<<<dim3(S_/32, B_*H_), blk, 0, stream>>>(
        q_raw, c_kv, kr_raw, w_uk_t, W_UV, offp, ctx);
    // 8. out = ctx @ W_O^T         [4096 x 2048]
    gemm_nt<<<dim3(2048/64, 4096/64), blk, 0, stream>>>(
        ctx, W_O, out, 4096, 2048, 2048, 2048, 2048, 2048);
}